// Round 8
// baseline (513.293 us; speedup 1.0000x reference)
//
#include <hip/hip_runtime.h>
#include <cstdint>
#include <cstddef>

typedef _Float16 f16;
typedef _Float16 half8 __attribute__((ext_vector_type(8)));
typedef float floatx4 __attribute__((ext_vector_type(4)));
typedef unsigned short ushort8 __attribute__((ext_vector_type(8)));

// async global->LDS, 16B per lane. LDS dest = wave-uniform base + lane*16.
__device__ __forceinline__ void gload_lds16(const void* g, void* l) {
    __builtin_amdgcn_global_load_lds(
        (const __attribute__((address_space(1))) void*)g,
        (__attribute__((address_space(3))) void*)l,
        16, 0, 0);
}

// f32 -> bf16 with round-to-nearest-even (bit trick; e>=0, finite here)
__device__ __forceinline__ unsigned short f32_to_bf16(float f) {
    unsigned u = __float_as_uint(f);
    return (unsigned short)((u + 0x7FFFu + ((u >> 16) & 1u)) >> 16);
}
__device__ __forceinline__ float bf16_to_f32(unsigned short h) {
    return __uint_as_float(((unsigned)h) << 16);
}

// ---- K0: fused preprocessing ----
// blocks [0,1024):   h_s f32 -> h_s16 (same layout) + h_sT16 (d-major transpose)
// blocks [1024,3104): f32 -> f16 convert for h_t (2048 blocks) and W (32 blocks)
__global__ void k_pre(const float* __restrict__ hs, f16* __restrict__ hs16, f16* __restrict__ hsT,
                      const float* __restrict__ ht, f16* __restrict__ ht16,
                      const float* __restrict__ W, f16* __restrict__ W16) {
    __shared__ f16 tile[64][65];
    int bid = blockIdx.x;
    int t = threadIdx.x;
    if (bid < 1024) {
        // transpose path: grid B * (S/64) * (D/64) = 4*64*4
        int dt = bid & 3;
        int st = (bid >> 2) & 63;
        int b  = bid >> 8;
        int s0 = st * 64, d0 = dt * 64;
#pragma unroll
        for (int i = 0; i < 16; i++) {
            int e = t + i * 256;
            int r = e >> 6, c = e & 63;
            float v = hs[((size_t)(b * 4096 + s0 + r)) * 256 + d0 + c];
            f16 hv = (f16)v;
            hs16[((size_t)(b * 4096 + s0 + r)) * 256 + d0 + c] = hv;
            tile[r][c] = hv;
        }
        __syncthreads();
#pragma unroll
        for (int i = 0; i < 16; i++) {
            int e = t + i * 256;
            int r = e >> 6, c = e & 63;  // r = d-local, c = s-local
            hsT[((size_t)(b * 256 + d0 + r)) * 4096 + s0 + c] = tile[c][r];
        }
    } else {
        int i = (bid - 1024) * 256 + t;
        const float* src;
        f16* dst;
        int j;
        if (i < 524288) { src = ht; dst = ht16; j = i; }
        else { j = i - 524288; if (j >= 8192) return; src = W; dst = W16; }
        const float4* s = (const float4*)src + 2 * (size_t)j;
        float4 a = s[0], b = s[1];
        half8 h;
        h[0] = (f16)a.x; h[1] = (f16)a.y; h[2] = (f16)a.z; h[3] = (f16)a.w;
        h[4] = (f16)b.x; h[5] = (f16)b.y; h[6] = (f16)b.z; h[7] = (f16)b.w;
        ((half8*)dst)[j] = h;
    }
}

// ---------------- K1: energy = h_s @ W^T  (M=4096 s, N=256 t, K=256) -> f16 ----------------
__global__ __launch_bounds__(256, 2) void k_energy(
    const f16* __restrict__ A,    // h_s16: B*4096*256 (K-contig)
    const f16* __restrict__ Bt,   // W16: 256*256 (N,K) row-major
    f16* __restrict__ C)          // energy16: B*4096*256 (s-major, tgt-contig)
{
    int id = blockIdx.x;
    int tn = id & 1, tm = (id >> 1) & 31, b = id >> 6;
    const f16* Ab = A + (size_t)b * 4096 * 256;

    __shared__ __align__(16) f16 As[128 * 64];
    __shared__ __align__(16) f16 Bs[128 * 64];

    int tid = threadIdx.x;
    int wave = tid >> 6, lane = tid & 63;
    int wr = wave >> 1, wc = wave & 1;
    int lm = lane & 15, lq = lane >> 4;

    floatx4 acc[4][4] = {};
    int r0 = tm * 128, c0 = tn * 128;

    for (int k0 = 0; k0 < 256; k0 += 64) {
#pragma unroll
        for (int i = 0; i < 4; i++) {
            int rbase = wave * 32 + i * 8;
            int row = rbase + (lane >> 3);
            gload_lds16(Ab + (size_t)(r0 + row) * 256 + k0 + (lane & 7) * 8, &As[rbase * 64]);
            gload_lds16(Bt + (size_t)(c0 + row) * 256 + k0 + (lane & 7) * 8, &Bs[rbase * 64]);
        }
        __syncthreads();
        half8 af[4][2], bf[4][2];
#pragma unroll
        for (int mi = 0; mi < 4; mi++)
#pragma unroll
            for (int kk = 0; kk < 2; kk++) {
                af[mi][kk] = *(const half8*)&As[(wr * 64 + mi * 16 + lm) * 64 + kk * 32 + lq * 8];
                bf[mi][kk] = *(const half8*)&Bs[(wc * 64 + mi * 16 + lm) * 64 + kk * 32 + lq * 8];
            }
#pragma unroll
        for (int kk = 0; kk < 2; kk++)
#pragma unroll
            for (int mi = 0; mi < 4; mi++)
#pragma unroll
                for (int ni = 0; ni < 4; ni++)
                    acc[mi][ni] = __builtin_amdgcn_mfma_f32_16x16x32_f16(af[mi][kk], bf[ni][kk], acc[mi][ni], 0, 0, 0);
        __syncthreads();
    }
#pragma unroll
    for (int mi = 0; mi < 4; mi++)
#pragma unroll
        for (int ni = 0; ni < 4; ni++)
#pragma unroll
            for (int r = 0; r < 4; r++) {
                int row = r0 + wr * 64 + mi * 16 + lq * 4 + r;
                int col = c0 + wc * 64 + ni * 16 + lm;
                C[(size_t)(b * 4096 + row) * 256 + col] = (f16)acc[mi][ni][r];
            }
}

// -------- K2: scores GEMM + mask -> store e=exp(score) as BF16; fused row sumexp atomics --------
// bf16 transport: full f32 exponent range (no max-subtract needed), half the write traffic.
// (256,2) launch bound: kernel wants ~150 VGPR; (256,4) forced spills (R7 regression).
// XCD pinning: batch b = (id&7)>>1 lives on one XCD pair; xcd&1 splits the tn range.
// Per-XCD L2 working set: A panel 2MB + B half-panel 1MB = 3MB (fits 4MB L2) ->
// tile re-reads (32x for A, 32x for B) become L2 hits instead of HBM fetches.
__global__ __launch_bounds__(256, 2) void k_scores(
    const f16* __restrict__ A,    // h_t16
    const f16* __restrict__ Bt,   // energy16
    const int* __restrict__ ms,   // B*S
    unsigned short* __restrict__ E, // workspace: B*T*S bf16 (exp(masked score))
    float* __restrict__ rsum)     // B*T, pre-zeroed; Σ_s exp(s) per row (no max shift)
{
    int id = blockIdx.x;
    int xcd = id & 7;                       // empirical id->XCD round-robin
    int b = xcd >> 1;                       // batch pinned to XCD pair
    int local = id >> 3;                    // 0..511, sweeps in time per XCD
    int tm = local >> 4;                    // 0..31 (A tiles stream)
    int tn = (local & 15) + ((xcd & 1) << 4);  // 0..31 (B half-panel resident)
    const f16* Ab = A + (size_t)b * 4096 * 256;
    const f16* Bb = Bt + (size_t)b * 4096 * 256;

    __shared__ __align__(16) f16 As[128 * 64];
    __shared__ __align__(16) f16 Bs[128 * 64];

    int tid = threadIdx.x;
    int wave = tid >> 6, lane = tid & 63;
    int wr = wave >> 1, wc = wave & 1;
    int lm = lane & 15, lq = lane >> 4;

    floatx4 acc[4][4] = {};
    int r0 = tm * 128, c0 = tn * 128;

    for (int k0 = 0; k0 < 256; k0 += 64) {
#pragma unroll
        for (int i = 0; i < 4; i++) {
            int rbase = wave * 32 + i * 8;
            int row = rbase + (lane >> 3);
            gload_lds16(Ab + (size_t)(r0 + row) * 256 + k0 + (lane & 7) * 8, &As[rbase * 64]);
            gload_lds16(Bb + (size_t)(c0 + row) * 256 + k0 + (lane & 7) * 8, &Bs[rbase * 64]);
        }
        __syncthreads();
        half8 af[4][2], bf[4][2];
#pragma unroll
        for (int mi = 0; mi < 4; mi++)
#pragma unroll
            for (int kk = 0; kk < 2; kk++) {
                af[mi][kk] = *(const half8*)&As[(wr * 64 + mi * 16 + lm) * 64 + kk * 32 + lq * 8];
                bf[mi][kk] = *(const half8*)&Bs[(wc * 64 + mi * 16 + lm) * 64 + kk * 32 + lq * 8];
            }
#pragma unroll
        for (int kk = 0; kk < 2; kk++)
#pragma unroll
            for (int mi = 0; mi < 4; mi++)
#pragma unroll
                for (int ni = 0; ni < 4; ni++)
                    acc[mi][ni] = __builtin_amdgcn_mfma_f32_16x16x32_f16(af[mi][kk], bf[ni][kk], acc[mi][ni], 0, 0, 0);
        __syncthreads();
    }
    // epilogue: e = mask ? exp(score) : 0; store bf16(e), accumulate f32 row sums
    float rs[4][4] = {};  // [mi][r]
#pragma unroll
    for (int ni = 0; ni < 4; ni++) {
        int col = c0 + wc * 64 + ni * 16 + lm;
        int m = ms[b * 4096 + col];
#pragma unroll
        for (int mi = 0; mi < 4; mi++)
#pragma unroll
            for (int r = 0; r < 4; r++) {
                int row = r0 + wr * 64 + mi * 16 + lq * 4 + r;
                float e = m ? __expf(acc[mi][ni][r]) : 0.0f;
                E[(size_t)(b * 4096 + row) * 4096 + col] = f32_to_bf16(e);
                rs[mi][r] += e;
            }
    }
#pragma unroll
    for (int mi = 0; mi < 4; mi++)
#pragma unroll
        for (int r = 0; r < 4; r++) {
            float v = rs[mi][r];
#pragma unroll
            for (int off = 1; off < 16; off <<= 1)
                v += __shfl_xor(v, off, 16);
            if (lm == 0) {
                int row = r0 + wr * 64 + mi * 16 + lq * 4 + r;
                atomicAdd(&rsum[b * 4096 + row], v);
            }
        }
}

// ------- K4: p = bf16(e)*rinv -> write p f32 + context partial GEMM (split-K, f16 partials) -------
// Register-neutral 2-phase: double-buffered LDS (Bs0/Bs1), ONE barrier per iter.
// NO e-prefetch (drained by barrier's implicit vmcnt(0) — proven regression R2/R6).
// XCD pinning: batch on XCD pair, ks-pair per XCD -> per-XCD resident hsT slices = 1MB,
// and all 64 of an XCD's blocks are co-resident -> hsT re-reads (32 tt-blocks) L2-hit.
// LDS B-tile uses chunked-XOR layout: chunk g (s/8) at g*4096 + (row ^ 2*(g&3))*16 bytes.
__global__ __launch_bounds__(256, 2) void k_ctx(
    const f16* __restrict__ BtT,          // h_sT16: B*256*4096
    const unsigned short* __restrict__ E, // bf16 e in workspace
    float* __restrict__ P,                // d_out scores region: normalized p (f32)
    const float* __restrict__ rsum,
    f16* __restrict__ part)               // 4 * B*4096*256 f16
{
    int id = blockIdx.x;
    int xcd = id & 7;
    int b = xcd >> 1;                       // batch pinned to XCD pair
    int local = id >> 3;                    // 0..63
    int ks = ((xcd & 1) << 1) | (local & 1);
    int tt = local >> 1;                    // 0..31
    int tid = threadIdx.x;
    int wave = tid >> 6, lane = tid & 63;
    int lm = lane & 15, lq = lane >> 4;

    __shared__ __align__(16) f16 Bs0[8 * 2048];  // 32KB chunked-swizzled, buffer 0
    __shared__ __align__(16) f16 Bs1[8 * 2048];  // buffer 1

    int t0 = tt * 128;
    const f16* Bb = BtT + (size_t)b * 256 * 4096;

    float rinv[2];
    size_t rowbase[2];
#pragma unroll
    for (int mi = 0; mi < 2; mi++) {
        int row = t0 + wave * 32 + mi * 16 + lm;
        int gr = b * 4096 + row;
        rinv[mi] = 1.0f / rsum[gr];
        rowbase[mi] = (size_t)gr * 4096;
    }

    // staging: this wave fills chunks g0,g1; lane's global row is XOR-permuted
    int g0 = wave * 2, g1 = wave * 2 + 1;
    int c0g = 2 * (g0 & 3), c1g = 2 * (g1 & 3);
    const f16* gp0 = Bb + (size_t)(lane ^ c0g) * 4096 + g0 * 8;
    const f16* gp1 = Bb + (size_t)(lane ^ c1g) * 4096 + g1 * 8;
    int lds_off0 = g0 * 2048, lds_off1 = g1 * 2048;

    // read-side lane bases (f16 elements): chunk (kk*4+lq), slot (lm ^ 2lq)
    int rbk[2];
    rbk[0] = (0 * 4 + lq) * 2048 + (lm ^ (2 * lq)) * 8;
    rbk[1] = (1 * 4 + lq) * 2048 + (lm ^ (2 * lq)) * 8;

    floatx4 acc[2][16] = {};
    int sbeg = ks * 1024;

    // ---- prologue: stage tile 0 into Bs0 ----
#pragma unroll
    for (int R = 0; R < 256; R += 64) {
        gload_lds16(gp0 + (size_t)R * 4096 + sbeg, &Bs0[lds_off0 + R * 8]);
        gload_lds16(gp1 + (size_t)R * 4096 + sbeg, &Bs0[lds_off1 + R * 8]);
    }
    __syncthreads();

    // Per iteration: {e-loads(it) first; stage(it+1)->write-buf; convert (waits only e-loads,
    //  counted vmcnt); p-write; 64 MFMA from read-buf; ONE barrier (drains stage(it+1),
    //  which had convert+p-write+MFMA (~700cyc) of cover)}.
#define CTX_ITER(IT, BSR, BSW) do { \
    int s0c_ = sbeg + (IT) * 64; \
    ushort8 ev_[2][2]; \
    _Pragma("unroll") \
    for (int mi = 0; mi < 2; mi++) \
        _Pragma("unroll") \
        for (int kk = 0; kk < 2; kk++) \
            ev_[mi][kk] = *(const ushort8*)(E + rowbase[mi] + s0c_ + kk * 32 + lq * 8); \
    if ((IT) < 15) { \
        int s0n_ = s0c_ + 64; \
        _Pragma("unroll") \
        for (int R = 0; R < 256; R += 64) { \
            gload_lds16(gp0 + (size_t)R * 4096 + s0n_, &BSW[lds_off0 + R * 8]); \
            gload_lds16(gp1 + (size_t)R * 4096 + s0n_, &BSW[lds_off1 + R * 8]); \
        } \
    } \
    half8 af_[2][2]; \
    _Pragma("unroll") \
    for (int mi = 0; mi < 2; mi++) \
        _Pragma("unroll") \
        for (int kk = 0; kk < 2; kk++) { \
            half8 h_; \
            _Pragma("unroll") \
            for (int j = 0; j < 8; j++) \
                h_[j] = (f16)(bf16_to_f32(ev_[mi][kk][j]) * rinv[mi]); \
            af_[mi][kk] = h_; \
        } \
    _Pragma("unroll") \
    for (int mi = 0; mi < 2; mi++) \
        _Pragma("unroll") \
        for (int kk = 0; kk < 2; kk++) { \
            float* p_ = P + rowbase[mi] + s0c_ + kk * 32 + lq * 8; \
            half8 h_ = af_[mi][kk]; \
            ((float4*)p_)[0] = make_float4((float)h_[0], (float)h_[1], (float)h_[2], (float)h_[3]); \
            ((float4*)p_)[1] = make_float4((float)h_[4], (float)h_[5], (float)h_[6], (float)h_[7]); \
        } \
    _Pragma("unroll") \
    for (int kk = 0; kk < 2; kk++) \
        _Pragma("unroll") \
        for (int ni = 0; ni < 16; ni++) { \
            half8 bf_ = *(const half8*)&BSR[rbk[kk] + ni * 128]; \
            _Pragma("unroll") \
            for (int mi = 0; mi < 2; mi++) \
                acc[mi][ni] = __builtin_amdgcn_mfma_f32_16x16x32_f16(af_[mi][kk], bf_, acc[mi][ni], 0, 0, 0); \
        } \
    __syncthreads(); \
    } while (0)

    for (int it = 0; it < 16; it += 2) {
        CTX_ITER(it, Bs0, Bs1);
        CTX_ITER(it + 1, Bs1, Bs0);
    }
#undef CTX_ITER

    f16* Pp = part + (size_t)ks * 4194304 + (size_t)b * 1048576;
#pragma unroll
    for (int mi = 0; mi < 2; mi++)
#pragma unroll
        for (int ni = 0; ni < 16; ni++)
#pragma unroll
            for (int r = 0; r < 4; r++) {
                int row = t0 + wave * 32 + mi * 16 + lq * 4 + r;
                int col = ni * 16 + lm;
                Pp[(size_t)row * 256 + col] = (f16)acc[mi][ni][r];
            }
}

// ---------------- K5: reduce 4 split-K f16 partials -> context f32 ----------------
__global__ void k_red(const f16* __restrict__ part, float* __restrict__ out) {
    size_t i = (size_t)blockIdx.x * 256 + threadIdx.x;  // half8 index, N8 = 524288
    const half8* p = (const half8*)part;
    half8 a = p[i];
    half8 b = p[i + 524288];
    half8 c = p[i + 1048576];
    half8 d = p[i + 1572864];
    float4 o0, o1;
    o0.x = (float)a[0] + (float)b[0] + (float)c[0] + (float)d[0];
    o0.y = (float)a[1] + (float)b[1] + (float)c[1] + (float)d[1];
    o0.z = (float)a[2] + (float)b[2] + (float)c[2] + (float)d[2];
    o0.w = (float)a[3] + (float)b[3] + (float)c[3] + (float)d[3];
    o1.x = (float)a[4] + (float)b[4] + (float)c[4] + (float)d[4];
    o1.y = (float)a[5] + (float)b[5] + (float)c[5] + (float)d[5];
    o1.z = (float)a[6] + (float)b[6] + (float)c[6] + (float)d[6];
    o1.w = (float)a[7] + (float)b[7] + (float)c[7] + (float)d[7];
    ((float4*)out)[2 * i] = o0;
    ((float4*)out)[2 * i + 1] = o1;
}

extern "C" void kernel_launch(void* const* d_in, const int* in_sizes, int n_in,
                              void* d_out, int out_size, void* d_ws, size_t ws_size,
                              hipStream_t stream) {
    const float* h_t = (const float*)d_in[0];   // 4*4096*256
    const float* h_s = (const float*)d_in[1];   // 4*4096*256
    const int*   m_s = (const int*)d_in[2];     // 4*4096
    const float* W   = (const float*)d_in[3];   // 256*256

    float* out = (float*)d_out;
    char* ws = (char*)d_ws;
    f16* h_t16 = (f16*)(ws);                      // 8.39 MB
    f16* h_s16 = (f16*)(ws + 8388608);            // 8.39 MB
    f16* h_sT  = (f16*)(ws + 16777216);           // 8.39 MB
    f16* en16  = (f16*)(ws + 25165824);           // 8.39 MB
    f16* W16   = (f16*)(ws + 33554432);           // 128 KB
    float* rsum = (float*)(ws + 33685504);        // 64 KB
    unsigned short* e16 = (unsigned short*)(ws + 33751040);  // 134.2 MB bf16 e
    f16* part = (f16*)(ws + 167968768);           // 33.6 MB f16 partials

    float* ctx = out;              // 4*4096*256 = 4194304
    float* sc  = out + 4194304;    // 4*4096*4096

    hipMemsetAsync(rsum, 0, 16384 * sizeof(float), stream);
    k_pre<<<3104, 256, 0, stream>>>(h_s, h_s16, h_sT, h_t, h_t16, W, W16);
    k_energy<<<256, 256, 0, stream>>>(h_s16, W16, en16);
    k_scores<<<4096, 256, 0, stream>>>(h_t16, en16, m_s, e16, rsum);
    k_ctx<<<512, 256, 0, stream>>>(h_sT, e16, sc, rsum, part);
    k_red<<<2048, 256, 0, stream>>>(part, ctx);
}

// Round 9
// 489.810 us; speedup vs baseline: 1.0479x; 1.0479x over previous
//
#include <hip/hip_runtime.h>
#include <cstdint>
#include <cstddef>

typedef _Float16 f16;
typedef _Float16 half8 __attribute__((ext_vector_type(8)));
typedef float floatx4 __attribute__((ext_vector_type(4)));
typedef unsigned short ushort8 __attribute__((ext_vector_type(8)));

// async global->LDS, 16B per lane. LDS dest = wave-uniform base + lane*16.
__device__ __forceinline__ void gload_lds16(const void* g, void* l) {
    __builtin_amdgcn_global_load_lds(
        (const __attribute__((address_space(1))) void*)g,
        (__attribute__((address_space(3))) void*)l,
        16, 0, 0);
}

// f32 -> bf16 with round-to-nearest-even (bit trick; e>=0, finite here)
__device__ __forceinline__ unsigned short f32_to_bf16(float f) {
    unsigned u = __float_as_uint(f);
    return (unsigned short)((u + 0x7FFFu + ((u >> 16) & 1u)) >> 16);
}
__device__ __forceinline__ float bf16_to_f32(unsigned short h) {
    return __uint_as_float(((unsigned)h) << 16);
}

// ---- K0: fused preprocessing ----
// blocks [0,16):     ALSO zero rsum (64KB) — replaces the hipMemsetAsync dispatch
// blocks [0,1024):   h_s f32 -> h_s16 (same layout) + h_sT16 (d-major transpose)
// blocks [1024,3104): f32 -> f16 convert for h_t (2048 blocks) and W (32 blocks)
__global__ void k_pre(const float* __restrict__ hs, f16* __restrict__ hs16, f16* __restrict__ hsT,
                      const float* __restrict__ ht, f16* __restrict__ ht16,
                      const float* __restrict__ W, f16* __restrict__ W16,
                      float* __restrict__ rsum) {
    __shared__ f16 tile[64][65];
    int bid = blockIdx.x;
    int t = threadIdx.x;
    if (bid < 16) {
        // zero rsum: 16 blocks x 256 threads x float4 = 16384 floats
        ((float4*)rsum)[bid * 256 + t] = make_float4(0.f, 0.f, 0.f, 0.f);
    }
    if (bid < 1024) {
        // transpose path: grid B * (S/64) * (D/64) = 4*64*4
        int dt = bid & 3;
        int st = (bid >> 2) & 63;
        int b  = bid >> 8;
        int s0 = st * 64, d0 = dt * 64;
#pragma unroll
        for (int i = 0; i < 16; i++) {
            int e = t + i * 256;
            int r = e >> 6, c = e & 63;
            float v = hs[((size_t)(b * 4096 + s0 + r)) * 256 + d0 + c];
            f16 hv = (f16)v;
            hs16[((size_t)(b * 4096 + s0 + r)) * 256 + d0 + c] = hv;
            tile[r][c] = hv;
        }
        __syncthreads();
#pragma unroll
        for (int i = 0; i < 16; i++) {
            int e = t + i * 256;
            int r = e >> 6, c = e & 63;  // r = d-local, c = s-local
            hsT[((size_t)(b * 256 + d0 + r)) * 4096 + s0 + c] = tile[c][r];
        }
    } else {
        int i = (bid - 1024) * 256 + t;
        const float* src;
        f16* dst;
        int j;
        if (i < 524288) { src = ht; dst = ht16; j = i; }
        else { j = i - 524288; if (j >= 8192) return; src = W; dst = W16; }
        const float4* s = (const float4*)src + 2 * (size_t)j;
        float4 a = s[0], b = s[1];
        half8 h;
        h[0] = (f16)a.x; h[1] = (f16)a.y; h[2] = (f16)a.z; h[3] = (f16)a.w;
        h[4] = (f16)b.x; h[5] = (f16)b.y; h[6] = (f16)b.z; h[7] = (f16)b.w;
        ((half8*)dst)[j] = h;
    }
}

// ---------------- K1: energy = h_s @ W^T  (M=4096 s, N=256 t, K=256) -> f16 ----------------
__global__ __launch_bounds__(256, 2) void k_energy(
    const f16* __restrict__ A,    // h_s16: B*4096*256 (K-contig)
    const f16* __restrict__ Bt,   // W16: 256*256 (N,K) row-major
    f16* __restrict__ C)          // energy16: B*4096*256 (s-major, tgt-contig)
{
    int id = blockIdx.x;
    int tn = id & 1, tm = (id >> 1) & 31, b = id >> 6;
    const f16* Ab = A + (size_t)b * 4096 * 256;

    __shared__ __align__(16) f16 As[128 * 64];
    __shared__ __align__(16) f16 Bs[128 * 64];

    int tid = threadIdx.x;
    int wave = tid >> 6, lane = tid & 63;
    int wr = wave >> 1, wc = wave & 1;
    int lm = lane & 15, lq = lane >> 4;

    floatx4 acc[4][4] = {};
    int r0 = tm * 128, c0 = tn * 128;

    for (int k0 = 0; k0 < 256; k0 += 64) {
#pragma unroll
        for (int i = 0; i < 4; i++) {
            int rbase = wave * 32 + i * 8;
            int row = rbase + (lane >> 3);
            gload_lds16(Ab + (size_t)(r0 + row) * 256 + k0 + (lane & 7) * 8, &As[rbase * 64]);
            gload_lds16(Bt + (size_t)(c0 + row) * 256 + k0 + (lane & 7) * 8, &Bs[rbase * 64]);
        }
        __syncthreads();
        half8 af[4][2], bf[4][2];
#pragma unroll
        for (int mi = 0; mi < 4; mi++)
#pragma unroll
            for (int kk = 0; kk < 2; kk++) {
                af[mi][kk] = *(const half8*)&As[(wr * 64 + mi * 16 + lm) * 64 + kk * 32 + lq * 8];
                bf[mi][kk] = *(const half8*)&Bs[(wc * 64 + mi * 16 + lm) * 64 + kk * 32 + lq * 8];
            }
#pragma unroll
        for (int kk = 0; kk < 2; kk++)
#pragma unroll
            for (int mi = 0; mi < 4; mi++)
#pragma unroll
                for (int ni = 0; ni < 4; ni++)
                    acc[mi][ni] = __builtin_amdgcn_mfma_f32_16x16x32_f16(af[mi][kk], bf[ni][kk], acc[mi][ni], 0, 0, 0);
        __syncthreads();
    }
#pragma unroll
    for (int mi = 0; mi < 4; mi++)
#pragma unroll
        for (int ni = 0; ni < 4; ni++)
#pragma unroll
            for (int r = 0; r < 4; r++) {
                int row = r0 + wr * 64 + mi * 16 + lq * 4 + r;
                int col = c0 + wc * 64 + ni * 16 + lm;
                C[(size_t)(b * 4096 + row) * 256 + col] = (f16)acc[mi][ni][r];
            }
}

// -------- K2: scores GEMM + mask -> store e=exp(score) as BF16; fused row sumexp atomics --------
// bf16 transport: full f32 exponent range (no max-subtract needed), half the write traffic.
// (256,2): kernel wants ~150 VGPR; forcing 128 via (256,4) spilled (R7 regression).
// Linear id decode: XCD pinning regressed (R8) — natural tm-major sweep is L2/L3-friendlier.
__global__ __launch_bounds__(256, 2) void k_scores(
    const f16* __restrict__ A,    // h_t16
    const f16* __restrict__ Bt,   // energy16
    const int* __restrict__ ms,   // B*S
    unsigned short* __restrict__ E, // workspace: B*T*S bf16 (exp(masked score))
    float* __restrict__ rsum)     // B*T, pre-zeroed; Σ_s exp(s) per row (no max shift)
{
    int id = blockIdx.x;
    int tn = id & 31, tm = (id >> 5) & 31, b = id >> 10;
    const f16* Ab = A + (size_t)b * 4096 * 256;
    const f16* Bb = Bt + (size_t)b * 4096 * 256;

    __shared__ __align__(16) f16 As[128 * 64];
    __shared__ __align__(16) f16 Bs[128 * 64];

    int tid = threadIdx.x;
    int wave = tid >> 6, lane = tid & 63;
    int wr = wave >> 1, wc = wave & 1;
    int lm = lane & 15, lq = lane >> 4;

    floatx4 acc[4][4] = {};
    int r0 = tm * 128, c0 = tn * 128;

    for (int k0 = 0; k0 < 256; k0 += 64) {
#pragma unroll
        for (int i = 0; i < 4; i++) {
            int rbase = wave * 32 + i * 8;
            int row = rbase + (lane >> 3);
            gload_lds16(Ab + (size_t)(r0 + row) * 256 + k0 + (lane & 7) * 8, &As[rbase * 64]);
            gload_lds16(Bb + (size_t)(c0 + row) * 256 + k0 + (lane & 7) * 8, &Bs[rbase * 64]);
        }
        __syncthreads();
        half8 af[4][2], bf[4][2];
#pragma unroll
        for (int mi = 0; mi < 4; mi++)
#pragma unroll
            for (int kk = 0; kk < 2; kk++) {
                af[mi][kk] = *(const half8*)&As[(wr * 64 + mi * 16 + lm) * 64 + kk * 32 + lq * 8];
                bf[mi][kk] = *(const half8*)&Bs[(wc * 64 + mi * 16 + lm) * 64 + kk * 32 + lq * 8];
            }
#pragma unroll
        for (int kk = 0; kk < 2; kk++)
#pragma unroll
            for (int mi = 0; mi < 4; mi++)
#pragma unroll
                for (int ni = 0; ni < 4; ni++)
                    acc[mi][ni] = __builtin_amdgcn_mfma_f32_16x16x32_f16(af[mi][kk], bf[ni][kk], acc[mi][ni], 0, 0, 0);
        __syncthreads();
    }
    // epilogue: e = mask ? exp(score) : 0; store bf16(e), accumulate f32 row sums
    float rs[4][4] = {};  // [mi][r]
#pragma unroll
    for (int ni = 0; ni < 4; ni++) {
        int col = c0 + wc * 64 + ni * 16 + lm;
        int m = ms[b * 4096 + col];
#pragma unroll
        for (int mi = 0; mi < 4; mi++)
#pragma unroll
            for (int r = 0; r < 4; r++) {
                int row = r0 + wr * 64 + mi * 16 + lq * 4 + r;
                float e = m ? __expf(acc[mi][ni][r]) : 0.0f;
                E[(size_t)(b * 4096 + row) * 4096 + col] = f32_to_bf16(e);
                rs[mi][r] += e;
            }
    }
#pragma unroll
    for (int mi = 0; mi < 4; mi++)
#pragma unroll
        for (int r = 0; r < 4; r++) {
            float v = rs[mi][r];
#pragma unroll
            for (int off = 1; off < 16; off <<= 1)
                v += __shfl_xor(v, off, 16);
            if (lm == 0) {
                int row = r0 + wr * 64 + mi * 16 + lq * 4 + r;
                atomicAdd(&rsum[b * 4096 + row], v);
            }
        }
}

// ------- K4: p = bf16(e)*rinv -> write p f32 + context partial GEMM (split-K, f16 partials) -------
// Register-neutral 2-phase (best verified, R3): double-buffered LDS (Bs0/Bs1), ONE barrier/iter.
// NO e-prefetch (drained by barrier's implicit vmcnt(0) — proven regression R2/R6).
// Linear id decode (XCD pinning regressed, R8). 4 waves, acc[2][16]; 8-wave variant neutral (R5).
// LDS B-tile uses chunked-XOR layout: chunk g (s/8) at g*4096 + (row ^ 2*(g&3))*16 bytes.
__global__ __launch_bounds__(256, 2) void k_ctx(
    const f16* __restrict__ BtT,          // h_sT16: B*256*4096
    const unsigned short* __restrict__ E, // bf16 e in workspace
    float* __restrict__ P,                // d_out scores region: normalized p (f32)
    const float* __restrict__ rsum,
    f16* __restrict__ part)               // 4 * B*4096*256 f16
{
    int id = blockIdx.x;
    int ks = id & 3, tt = (id >> 2) & 31, b = id >> 7;
    int tid = threadIdx.x;
    int wave = tid >> 6, lane = tid & 63;
    int lm = lane & 15, lq = lane >> 4;

    __shared__ __align__(16) f16 Bs0[8 * 2048];  // 32KB chunked-swizzled, buffer 0
    __shared__ __align__(16) f16 Bs1[8 * 2048];  // buffer 1

    int t0 = tt * 128;
    const f16* Bb = BtT + (size_t)b * 256 * 4096;

    float rinv[2];
    size_t rowbase[2];
#pragma unroll
    for (int mi = 0; mi < 2; mi++) {
        int row = t0 + wave * 32 + mi * 16 + lm;
        int gr = b * 4096 + row;
        rinv[mi] = 1.0f / rsum[gr];
        rowbase[mi] = (size_t)gr * 4096;
    }

    // staging: this wave fills chunks g0,g1; lane's global row is XOR-permuted
    int g0 = wave * 2, g1 = wave * 2 + 1;
    int c0g = 2 * (g0 & 3), c1g = 2 * (g1 & 3);
    const f16* gp0 = Bb + (size_t)(lane ^ c0g) * 4096 + g0 * 8;
    const f16* gp1 = Bb + (size_t)(lane ^ c1g) * 4096 + g1 * 8;
    int lds_off0 = g0 * 2048, lds_off1 = g1 * 2048;

    // read-side lane bases (f16 elements): chunk (kk*4+lq), slot (lm ^ 2lq)
    int rbk[2];
    rbk[0] = (0 * 4 + lq) * 2048 + (lm ^ (2 * lq)) * 8;
    rbk[1] = (1 * 4 + lq) * 2048 + (lm ^ (2 * lq)) * 8;

    floatx4 acc[2][16] = {};
    int sbeg = ks * 1024;

    // ---- prologue: stage tile 0 into Bs0 ----
#pragma unroll
    for (int R = 0; R < 256; R += 64) {
        gload_lds16(gp0 + (size_t)R * 4096 + sbeg, &Bs0[lds_off0 + R * 8]);
        gload_lds16(gp1 + (size_t)R * 4096 + sbeg, &Bs0[lds_off1 + R * 8]);
    }
    __syncthreads();

    // Per iteration: {e-loads(it) first; stage(it+1)->write-buf; convert (waits only e-loads,
    //  counted vmcnt); p-write; 64 MFMA from read-buf; ONE barrier (drains stage(it+1),
    //  which had convert+p-write+MFMA (~700cyc) of cover)}.
#define CTX_ITER(IT, BSR, BSW) do { \
    int s0c_ = sbeg + (IT) * 64; \
    ushort8 ev_[2][2]; \
    _Pragma("unroll") \
    for (int mi = 0; mi < 2; mi++) \
        _Pragma("unroll") \
        for (int kk = 0; kk < 2; kk++) \
            ev_[mi][kk] = *(const ushort8*)(E + rowbase[mi] + s0c_ + kk * 32 + lq * 8); \
    if ((IT) < 15) { \
        int s0n_ = s0c_ + 64; \
        _Pragma("unroll") \
        for (int R = 0; R < 256; R += 64) { \
            gload_lds16(gp0 + (size_t)R * 4096 + s0n_, &BSW[lds_off0 + R * 8]); \
            gload_lds16(gp1 + (size_t)R * 4096 + s0n_, &BSW[lds_off1 + R * 8]); \
        } \
    } \
    half8 af_[2][2]; \
    _Pragma("unroll") \
    for (int mi = 0; mi < 2; mi++) \
        _Pragma("unroll") \
        for (int kk = 0; kk < 2; kk++) { \
            half8 h_; \
            _Pragma("unroll") \
            for (int j = 0; j < 8; j++) \
                h_[j] = (f16)(bf16_to_f32(ev_[mi][kk][j]) * rinv[mi]); \
            af_[mi][kk] = h_; \
        } \
    _Pragma("unroll") \
    for (int mi = 0; mi < 2; mi++) \
        _Pragma("unroll") \
        for (int kk = 0; kk < 2; kk++) { \
            float* p_ = P + rowbase[mi] + s0c_ + kk * 32 + lq * 8; \
            half8 h_ = af_[mi][kk]; \
            ((float4*)p_)[0] = make_float4((float)h_[0], (float)h_[1], (float)h_[2], (float)h_[3]); \
            ((float4*)p_)[1] = make_float4((float)h_[4], (float)h_[5], (float)h_[6], (float)h_[7]); \
        } \
    _Pragma("unroll") \
    for (int kk = 0; kk < 2; kk++) \
        _Pragma("unroll") \
        for (int ni = 0; ni < 16; ni++) { \
            half8 bf_ = *(const half8*)&BSR[rbk[kk] + ni * 128]; \
            _Pragma("unroll") \
            for (int mi = 0; mi < 2; mi++) \
                acc[mi][ni] = __builtin_amdgcn_mfma_f32_16x16x32_f16(af_[mi][kk], bf_, acc[mi][ni], 0, 0, 0); \
        } \
    __syncthreads(); \
    } while (0)

    for (int it = 0; it < 16; it += 2) {
        CTX_ITER(it, Bs0, Bs1);
        CTX_ITER(it + 1, Bs1, Bs0);
    }
#undef CTX_ITER

    f16* Pp = part + (size_t)ks * 4194304 + (size_t)b * 1048576;
#pragma unroll
    for (int mi = 0; mi < 2; mi++)
#pragma unroll
        for (int ni = 0; ni < 16; ni++)
#pragma unroll
            for (int r = 0; r < 4; r++) {
                int row = t0 + wave * 32 + mi * 16 + lq * 4 + r;
                int col = ni * 16 + lm;
                Pp[(size_t)row * 256 + col] = (f16)acc[mi][ni][r];
            }
}

// ---------------- K5: reduce 4 split-K f16 partials -> context f32 ----------------
__global__ void k_red(const f16* __restrict__ part, float* __restrict__ out) {
    size_t i = (size_t)blockIdx.x * 256 + threadIdx.x;  // half8 index, N8 = 524288
    const half8* p = (const half8*)part;
    half8 a = p[i];
    half8 b = p[i + 524288];
    half8 c = p[i + 1048576];
    half8 d = p[i + 1572864];
    float4 o0, o1;
    o0.x = (float)a[0] + (float)b[0] + (float)c[0] + (float)d[0];
    o0.y = (float)a[1] + (float)b[1] + (float)c[1] + (float)d[1];
    o0.z = (float)a[2] + (float)b[2] + (float)c[2] + (float)d[2];
    o0.w = (float)a[3] + (float)b[3] + (float)c[3] + (float)d[3];
    o1.x = (float)a[4] + (float)b[4] + (float)c[4] + (float)d[4];
    o1.y = (float)a[5] + (float)b[5] + (float)c[5] + (float)d[5];
    o1.z = (float)a[6] + (float)b[6] + (float)c[6] + (float)d[6];
    o1.w = (float)a[7] + (float)b[7] + (float)c[7] + (float)d[7];
    ((float4*)out)[2 * i] = o0;
    ((float4*)out)[2 * i + 1] = o1;
}

extern "C" void kernel_launch(void* const* d_in, const int* in_sizes, int n_in,
                              void* d_out, int out_size, void* d_ws, size_t ws_size,
                              hipStream_t stream) {
    const float* h_t = (const float*)d_in[0];   // 4*4096*256
    const float* h_s = (const float*)d_in[1];   // 4*4096*256
    const int*   m_s = (const int*)d_in[2];     // 4*4096
    const float* W   = (const float*)d_in[3];   // 256*256

    float* out = (float*)d_out;
    char* ws = (char*)d_ws;
    f16* h_t16 = (f16*)(ws);                      // 8.39 MB
    f16* h_s16 = (f16*)(ws + 8388608);            // 8.39 MB
    f16* h_sT  = (f16*)(ws + 16777216);           // 8.39 MB
    f16* en16  = (f16*)(ws + 25165824);           // 8.39 MB
    f16* W16   = (f16*)(ws + 33554432);           // 128 KB
    float* rsum = (float*)(ws + 33685504);        // 64 KB
    unsigned short* e16 = (unsigned short*)(ws + 33751040);  // 134.2 MB bf16 e
    f16* part = (f16*)(ws + 167968768);           // 33.6 MB f16 partials

    float* ctx = out;              // 4*4096*256 = 4194304
    float* sc  = out + 4194304;    // 4*4096*4096

    k_pre<<<3104, 256, 0, stream>>>(h_s, h_s16, h_sT, h_t, h_t16, W, W16, rsum);
    k_energy<<<256, 256, 0, stream>>>(h_s16, W16, en16);
    k_scores<<<4096, 256, 0, stream>>>(h_t16, en16, m_s, e16, rsum);
    k_ctx<<<512, 256, 0, stream>>>(h_sT, e16, sc, rsum, part);
    k_red<<<2048, 256, 0, stream>>>(part, ctx);
}

// Round 10
// 489.266 us; speedup vs baseline: 1.0491x; 1.0011x over previous
//
#include <hip/hip_runtime.h>
#include <cstdint>
#include <cstddef>

typedef _Float16 f16;
typedef _Float16 half8 __attribute__((ext_vector_type(8)));
typedef float floatx4 __attribute__((ext_vector_type(4)));
typedef unsigned short ushort8 __attribute__((ext_vector_type(8)));

// async global->LDS, 16B per lane. LDS dest = wave-uniform base + lane*16.
__device__ __forceinline__ void gload_lds16(const void* g, void* l) {
    __builtin_amdgcn_global_load_lds(
        (const __attribute__((address_space(1))) void*)g,
        (__attribute__((address_space(3))) void*)l,
        16, 0, 0);
}

// f32 -> bf16 with round-to-nearest-even (bit trick; e>=0, finite here)
__device__ __forceinline__ unsigned short f32_to_bf16(float f) {
    unsigned u = __float_as_uint(f);
    return (unsigned short)((u + 0x7FFFu + ((u >> 16) & 1u)) >> 16);
}
__device__ __forceinline__ float bf16_to_f32(unsigned short h) {
    return __uint_as_float(((unsigned)h) << 16);
}

// ---- K0: fused preprocessing ----
// blocks [0,16):     ALSO zero rsum (64KB) — replaces the hipMemsetAsync dispatch
// blocks [0,1024):   h_s f32 -> h_s16 (same layout) + h_sT16 (d-major transpose)
// blocks [1024,3104): f32 -> f16 convert for h_t (2048 blocks) and W (32 blocks)
__global__ void k_pre(const float* __restrict__ hs, f16* __restrict__ hs16, f16* __restrict__ hsT,
                      const float* __restrict__ ht, f16* __restrict__ ht16,
                      const float* __restrict__ W, f16* __restrict__ W16,
                      float* __restrict__ rsum) {
    __shared__ f16 tile[64][65];
    int bid = blockIdx.x;
    int t = threadIdx.x;
    if (bid < 16) {
        // zero rsum: 16 blocks x 256 threads x float4 = 16384 floats
        ((float4*)rsum)[bid * 256 + t] = make_float4(0.f, 0.f, 0.f, 0.f);
    }
    if (bid < 1024) {
        // transpose path: grid B * (S/64) * (D/64) = 4*64*4
        int dt = bid & 3;
        int st = (bid >> 2) & 63;
        int b  = bid >> 8;
        int s0 = st * 64, d0 = dt * 64;
#pragma unroll
        for (int i = 0; i < 16; i++) {
            int e = t + i * 256;
            int r = e >> 6, c = e & 63;
            float v = hs[((size_t)(b * 4096 + s0 + r)) * 256 + d0 + c];
            f16 hv = (f16)v;
            hs16[((size_t)(b * 4096 + s0 + r)) * 256 + d0 + c] = hv;
            tile[r][c] = hv;
        }
        __syncthreads();
#pragma unroll
        for (int i = 0; i < 16; i++) {
            int e = t + i * 256;
            int r = e >> 6, c = e & 63;  // r = d-local, c = s-local
            hsT[((size_t)(b * 256 + d0 + r)) * 4096 + s0 + c] = tile[c][r];
        }
    } else {
        int i = (bid - 1024) * 256 + t;
        const float* src;
        f16* dst;
        int j;
        if (i < 524288) { src = ht; dst = ht16; j = i; }
        else { j = i - 524288; if (j >= 8192) return; src = W; dst = W16; }
        const float4* s = (const float4*)src + 2 * (size_t)j;
        float4 a = s[0], b = s[1];
        half8 h;
        h[0] = (f16)a.x; h[1] = (f16)a.y; h[2] = (f16)a.z; h[3] = (f16)a.w;
        h[4] = (f16)b.x; h[5] = (f16)b.y; h[6] = (f16)b.z; h[7] = (f16)b.w;
        ((half8*)dst)[j] = h;
    }
}

// ---------------- K1: energy = h_s @ W^T  (M=4096 s, N=256 t, K=256) -> f16 ----------------
// 64x128 tile (was 128x128): grid 512 = 2 blocks/CU (was 256 = 1 block/CU, 1 wave/SIMD —
// worst-case latency exposure). acc[2][4]=32 VGPR/wave (was 128), LDS 24KB (was 64KB).
// Same staging scheme (8 rows/wave/round), same fragment formulas, wr stride 32.
__global__ __launch_bounds__(256, 2) void k_energy(
    const f16* __restrict__ A,    // h_s16: B*4096*256 (K-contig)
    const f16* __restrict__ Bt,   // W16: 256*256 (N,K) row-major
    f16* __restrict__ C)          // energy16: B*4096*256 (s-major, tgt-contig)
{
    int id = blockIdx.x;
    int tn = id & 1, tm = (id >> 1) & 63, b = id >> 7;
    const f16* Ab = A + (size_t)b * 4096 * 256;

    __shared__ __align__(16) f16 As[64 * 64];    // 8KB
    __shared__ __align__(16) f16 Bs[128 * 64];   // 16KB

    int tid = threadIdx.x;
    int wave = tid >> 6, lane = tid & 63;
    int wr = wave >> 1, wc = wave & 1;
    int lm = lane & 15, lq = lane >> 4;

    floatx4 acc[2][4] = {};
    int r0 = tm * 64, c0 = tn * 128;

    for (int k0 = 0; k0 < 256; k0 += 64) {
        // A: 64 rows x 64 k -> 2 rounds (8 rows per wave per round)
#pragma unroll
        for (int i = 0; i < 2; i++) {
            int rbase = wave * 16 + i * 8;
            int row = rbase + (lane >> 3);
            gload_lds16(Ab + (size_t)(r0 + row) * 256 + k0 + (lane & 7) * 8, &As[rbase * 64]);
        }
        // B: 128 rows x 64 k -> 4 rounds
#pragma unroll
        for (int i = 0; i < 4; i++) {
            int rbase = wave * 32 + i * 8;
            int row = rbase + (lane >> 3);
            gload_lds16(Bt + (size_t)(c0 + row) * 256 + k0 + (lane & 7) * 8, &Bs[rbase * 64]);
        }
        __syncthreads();
        half8 af[2][2], bf[4][2];
#pragma unroll
        for (int kk = 0; kk < 2; kk++) {
#pragma unroll
            for (int mi = 0; mi < 2; mi++)
                af[mi][kk] = *(const half8*)&As[(wr * 32 + mi * 16 + lm) * 64 + kk * 32 + lq * 8];
#pragma unroll
            for (int ni = 0; ni < 4; ni++)
                bf[ni][kk] = *(const half8*)&Bs[(wc * 64 + ni * 16 + lm) * 64 + kk * 32 + lq * 8];
        }
#pragma unroll
        for (int kk = 0; kk < 2; kk++)
#pragma unroll
            for (int mi = 0; mi < 2; mi++)
#pragma unroll
                for (int ni = 0; ni < 4; ni++)
                    acc[mi][ni] = __builtin_amdgcn_mfma_f32_16x16x32_f16(af[mi][kk], bf[ni][kk], acc[mi][ni], 0, 0, 0);
        __syncthreads();
    }
#pragma unroll
    for (int mi = 0; mi < 2; mi++)
#pragma unroll
        for (int ni = 0; ni < 4; ni++)
#pragma unroll
            for (int r = 0; r < 4; r++) {
                int row = r0 + wr * 32 + mi * 16 + lq * 4 + r;
                int col = c0 + wc * 64 + ni * 16 + lm;
                C[(size_t)(b * 4096 + row) * 256 + col] = (f16)acc[mi][ni][r];
            }
}

// -------- K2: scores GEMM + mask -> store e=exp(score) as BF16; fused row sumexp atomics --------
// bf16 transport: full f32 exponent range (no max-subtract needed), half the write traffic.
// (256,2): kernel wants ~150 VGPR; forcing 128 via (256,4) spilled (R7 regression).
// Linear id decode: XCD pinning regressed (R8) — natural tm-major sweep is L2/L3-friendlier.
__global__ __launch_bounds__(256, 2) void k_scores(
    const f16* __restrict__ A,    // h_t16
    const f16* __restrict__ Bt,   // energy16
    const int* __restrict__ ms,   // B*S
    unsigned short* __restrict__ E, // workspace: B*T*S bf16 (exp(masked score))
    float* __restrict__ rsum)     // B*T, pre-zeroed; Σ_s exp(s) per row (no max shift)
{
    int id = blockIdx.x;
    int tn = id & 31, tm = (id >> 5) & 31, b = id >> 10;
    const f16* Ab = A + (size_t)b * 4096 * 256;
    const f16* Bb = Bt + (size_t)b * 4096 * 256;

    __shared__ __align__(16) f16 As[128 * 64];
    __shared__ __align__(16) f16 Bs[128 * 64];

    int tid = threadIdx.x;
    int wave = tid >> 6, lane = tid & 63;
    int wr = wave >> 1, wc = wave & 1;
    int lm = lane & 15, lq = lane >> 4;

    floatx4 acc[4][4] = {};
    int r0 = tm * 128, c0 = tn * 128;

    for (int k0 = 0; k0 < 256; k0 += 64) {
#pragma unroll
        for (int i = 0; i < 4; i++) {
            int rbase = wave * 32 + i * 8;
            int row = rbase + (lane >> 3);
            gload_lds16(Ab + (size_t)(r0 + row) * 256 + k0 + (lane & 7) * 8, &As[rbase * 64]);
            gload_lds16(Bb + (size_t)(c0 + row) * 256 + k0 + (lane & 7) * 8, &Bs[rbase * 64]);
        }
        __syncthreads();
        half8 af[4][2], bf[4][2];
#pragma unroll
        for (int mi = 0; mi < 4; mi++)
#pragma unroll
            for (int kk = 0; kk < 2; kk++) {
                af[mi][kk] = *(const half8*)&As[(wr * 64 + mi * 16 + lm) * 64 + kk * 32 + lq * 8];
                bf[mi][kk] = *(const half8*)&Bs[(wc * 64 + mi * 16 + lm) * 64 + kk * 32 + lq * 8];
            }
#pragma unroll
        for (int kk = 0; kk < 2; kk++)
#pragma unroll
            for (int mi = 0; mi < 4; mi++)
#pragma unroll
                for (int ni = 0; ni < 4; ni++)
                    acc[mi][ni] = __builtin_amdgcn_mfma_f32_16x16x32_f16(af[mi][kk], bf[ni][kk], acc[mi][ni], 0, 0, 0);
        __syncthreads();
    }
    // epilogue: e = mask ? exp(score) : 0; store bf16(e), accumulate f32 row sums
    float rs[4][4] = {};  // [mi][r]
#pragma unroll
    for (int ni = 0; ni < 4; ni++) {
        int col = c0 + wc * 64 + ni * 16 + lm;
        int m = ms[b * 4096 + col];
#pragma unroll
        for (int mi = 0; mi < 4; mi++)
#pragma unroll
            for (int r = 0; r < 4; r++) {
                int row = r0 + wr * 64 + mi * 16 + lq * 4 + r;
                float e = m ? __expf(acc[mi][ni][r]) : 0.0f;
                E[(size_t)(b * 4096 + row) * 4096 + col] = f32_to_bf16(e);
                rs[mi][r] += e;
            }
    }
#pragma unroll
    for (int mi = 0; mi < 4; mi++)
#pragma unroll
        for (int r = 0; r < 4; r++) {
            float v = rs[mi][r];
#pragma unroll
            for (int off = 1; off < 16; off <<= 1)
                v += __shfl_xor(v, off, 16);
            if (lm == 0) {
                int row = r0 + wr * 64 + mi * 16 + lq * 4 + r;
                atomicAdd(&rsum[b * 4096 + row], v);
            }
        }
}

// ------- K4: p = bf16(e)*rinv -> write p f32 + context partial GEMM (split-K, f16 partials) -------
// Register-neutral 2-phase (best verified, R3): double-buffered LDS (Bs0/Bs1), ONE barrier/iter.
// NO e-prefetch (drained by barrier's implicit vmcnt(0) — proven regression R2/R6).
// Linear id decode (XCD pinning regressed, R8). 4 waves, acc[2][16]; 8-wave variant neutral (R5).
// LDS B-tile uses chunked-XOR layout: chunk g (s/8) at g*4096 + (row ^ 2*(g&3))*16 bytes.
__global__ __launch_bounds__(256, 2) void k_ctx(
    const f16* __restrict__ BtT,          // h_sT16: B*256*4096
    const unsigned short* __restrict__ E, // bf16 e in workspace
    float* __restrict__ P,                // d_out scores region: normalized p (f32)
    const float* __restrict__ rsum,
    f16* __restrict__ part)               // 4 * B*4096*256 f16
{
    int id = blockIdx.x;
    int ks = id & 3, tt = (id >> 2) & 31, b = id >> 7;
    int tid = threadIdx.x;
    int wave = tid >> 6, lane = tid & 63;
    int lm = lane & 15, lq = lane >> 4;

    __shared__ __align__(16) f16 Bs0[8 * 2048];  // 32KB chunked-swizzled, buffer 0
    __shared__ __align__(16) f16 Bs1[8 * 2048];  // buffer 1

    int t0 = tt * 128;
    const f16* Bb = BtT + (size_t)b * 256 * 4096;

    float rinv[2];
    size_t rowbase[2];
#pragma unroll
    for (int mi = 0; mi < 2; mi++) {
        int row = t0 + wave * 32 + mi * 16 + lm;
        int gr = b * 4096 + row;
        rinv[mi] = 1.0f / rsum[gr];
        rowbase[mi] = (size_t)gr * 4096;
    }

    // staging: this wave fills chunks g0,g1; lane's global row is XOR-permuted
    int g0 = wave * 2, g1 = wave * 2 + 1;
    int c0g = 2 * (g0 & 3), c1g = 2 * (g1 & 3);
    const f16* gp0 = Bb + (size_t)(lane ^ c0g) * 4096 + g0 * 8;
    const f16* gp1 = Bb + (size_t)(lane ^ c1g) * 4096 + g1 * 8;
    int lds_off0 = g0 * 2048, lds_off1 = g1 * 2048;

    // read-side lane bases (f16 elements): chunk (kk*4+lq), slot (lm ^ 2lq)
    int rbk[2];
    rbk[0] = (0 * 4 + lq) * 2048 + (lm ^ (2 * lq)) * 8;
    rbk[1] = (1 * 4 + lq) * 2048 + (lm ^ (2 * lq)) * 8;

    floatx4 acc[2][16] = {};
    int sbeg = ks * 1024;

    // ---- prologue: stage tile 0 into Bs0 ----
#pragma unroll
    for (int R = 0; R < 256; R += 64) {
        gload_lds16(gp0 + (size_t)R * 4096 + sbeg, &Bs0[lds_off0 + R * 8]);
        gload_lds16(gp1 + (size_t)R * 4096 + sbeg, &Bs0[lds_off1 + R * 8]);
    }
    __syncthreads();

    // Per iteration: {e-loads(it) first; stage(it+1)->write-buf; convert (waits only e-loads,
    //  counted vmcnt); p-write; 64 MFMA from read-buf; ONE barrier (drains stage(it+1),
    //  which had convert+p-write+MFMA (~700cyc) of cover)}.
#define CTX_ITER(IT, BSR, BSW) do { \
    int s0c_ = sbeg + (IT) * 64; \
    ushort8 ev_[2][2]; \
    _Pragma("unroll") \
    for (int mi = 0; mi < 2; mi++) \
        _Pragma("unroll") \
        for (int kk = 0; kk < 2; kk++) \
            ev_[mi][kk] = *(const ushort8*)(E + rowbase[mi] + s0c_ + kk * 32 + lq * 8); \
    if ((IT) < 15) { \
        int s0n_ = s0c_ + 64; \
        _Pragma("unroll") \
        for (int R = 0; R < 256; R += 64) { \
            gload_lds16(gp0 + (size_t)R * 4096 + s0n_, &BSW[lds_off0 + R * 8]); \
            gload_lds16(gp1 + (size_t)R * 4096 + s0n_, &BSW[lds_off1 + R * 8]); \
        } \
    } \
    half8 af_[2][2]; \
    _Pragma("unroll") \
    for (int mi = 0; mi < 2; mi++) \
        _Pragma("unroll") \
        for (int kk = 0; kk < 2; kk++) { \
            half8 h_; \
            _Pragma("unroll") \
            for (int j = 0; j < 8; j++) \
                h_[j] = (f16)(bf16_to_f32(ev_[mi][kk][j]) * rinv[mi]); \
            af_[mi][kk] = h_; \
        } \
    _Pragma("unroll") \
    for (int mi = 0; mi < 2; mi++) \
        _Pragma("unroll") \
        for (int kk = 0; kk < 2; kk++) { \
            float* p_ = P + rowbase[mi] + s0c_ + kk * 32 + lq * 8; \
            half8 h_ = af_[mi][kk]; \
            ((float4*)p_)[0] = make_float4((float)h_[0], (float)h_[1], (float)h_[2], (float)h_[3]); \
            ((float4*)p_)[1] = make_float4((float)h_[4], (float)h_[5], (float)h_[6], (float)h_[7]); \
        } \
    _Pragma("unroll") \
    for (int kk = 0; kk < 2; kk++) \
        _Pragma("unroll") \
        for (int ni = 0; ni < 16; ni++) { \
            half8 bf_ = *(const half8*)&BSR[rbk[kk] + ni * 128]; \
            _Pragma("unroll") \
            for (int mi = 0; mi < 2; mi++) \
                acc[mi][ni] = __builtin_amdgcn_mfma_f32_16x16x32_f16(af_[mi][kk], bf_, acc[mi][ni], 0, 0, 0); \
        } \
    __syncthreads(); \
    } while (0)

    for (int it = 0; it < 16; it += 2) {
        CTX_ITER(it, Bs0, Bs1);
        CTX_ITER(it + 1, Bs1, Bs0);
    }
#undef CTX_ITER

    f16* Pp = part + (size_t)ks * 4194304 + (size_t)b * 1048576;
#pragma unroll
    for (int mi = 0; mi < 2; mi++)
#pragma unroll
        for (int ni = 0; ni < 16; ni++)
#pragma unroll
            for (int r = 0; r < 4; r++) {
                int row = t0 + wave * 32 + mi * 16 + lq * 4 + r;
                int col = ni * 16 + lm;
                Pp[(size_t)row * 256 + col] = (f16)acc[mi][ni][r];
            }
}

// ---------------- K5: reduce 4 split-K f16 partials -> context f32 ----------------
__global__ void k_red(const f16* __restrict__ part, float* __restrict__ out) {
    size_t i = (size_t)blockIdx.x * 256 + threadIdx.x;  // half8 index, N8 = 524288
    const half8* p = (const half8*)part;
    half8 a = p[i];
    half8 b = p[i + 524288];
    half8 c = p[i + 1048576];
    half8 d = p[i + 1572864];
    float4 o0, o1;
    o0.x = (float)a[0] + (float)b[0] + (float)c[0] + (float)d[0];
    o0.y = (float)a[1] + (float)b[1] + (float)c[1] + (float)d[1];
    o0.z = (float)a[2] + (float)b[2] + (float)c[2] + (float)d[2];
    o0.w = (float)a[3] + (float)b[3] + (float)c[3] + (float)d[3];
    o1.x = (float)a[4] + (float)b[4] + (float)c[4] + (float)d[4];
    o1.y = (float)a[5] + (float)b[5] + (float)c[5] + (float)d[5];
    o1.z = (float)a[6] + (float)b[6] + (float)c[6] + (float)d[6];
    o1.w = (float)a[7] + (float)b[7] + (float)c[7] + (float)d[7];
    ((float4*)out)[2 * i] = o0;
    ((float4*)out)[2 * i + 1] = o1;
}

extern "C" void kernel_launch(void* const* d_in, const int* in_sizes, int n_in,
                              void* d_out, int out_size, void* d_ws, size_t ws_size,
                              hipStream_t stream) {
    const float* h_t = (const float*)d_in[0];   // 4*4096*256
    const float* h_s = (const float*)d_in[1];   // 4*4096*256
    const int*   m_s = (const int*)d_in[2];     // 4*4096
    const float* W   = (const float*)d_in[3];   // 256*256

    float* out = (float*)d_out;
    char* ws = (char*)d_ws;
    f16* h_t16 = (f16*)(ws);                      // 8.39 MB
    f16* h_s16 = (f16*)(ws + 8388608);            // 8.39 MB
    f16* h_sT  = (f16*)(ws + 16777216);           // 8.39 MB
    f16* en16  = (f16*)(ws + 25165824);           // 8.39 MB
    f16* W16   = (f16*)(ws + 33554432);           // 128 KB
    float* rsum = (float*)(ws + 33685504);        // 64 KB
    unsigned short* e16 = (unsigned short*)(ws + 33751040);  // 134.2 MB bf16 e
    f16* part = (f16*)(ws + 167968768);           // 33.6 MB f16 partials

    float* ctx = out;              // 4*4096*256 = 4194304
    float* sc  = out + 4194304;    // 4*4096*4096

    k_pre<<<3104, 256, 0, stream>>>(h_s, h_s16, h_sT, h_t, h_t16, W, W16, rsum);
    k_energy<<<512, 256, 0, stream>>>(h_s16, W16, en16);
    k_scores<<<4096, 256, 0, stream>>>(h_t16, en16, m_s, e16, rsum);
    k_ctx<<<512, 256, 0, stream>>>(h_sT, e16, sc, rsum, part);
    k_red<<<2048, 256, 0, stream>>>(part, ctx);
}